// Round 1
// baseline (970.855 us; speedup 1.0000x reference)
//
#include <hip/hip_runtime.h>
#include <hip/hip_bf16.h>
#include <cstdint>
#include <cstddef>

// Problem constants
#define BATCH 8
#define HH 128
#define WW 128
#define CC 256
#define NHEADS 8
#define KK 7
#define MTOT (BATCH * HH * WW)   // 131072 rows

// ---------------------------------------------------------------------------
// GEMM: C[M,256] = A[M,256] @ W[256,256]^T + bias
//   C[m,n] = dot(A[m,:], W[n,:]) + bias[n]
// 128x128 tile per block, BK=16, 256 threads, 8x8 acc per thread.
// LDS layout transposed [k][m] so inner-loop reads are ds_read_b128.
// Thread (tx,ty) owns rows {ty*4..+3, 64+ty*4..+3} x cols {tx*4..+3, 64+tx*4..+3}
// -> 16-lane read groups cover contiguous 256B (2-way bank alias = free).
// ---------------------------------------------------------------------------
#define BK 16

__global__ __launch_bounds__(256) void gemm_bt_bias_f32(
    const float* __restrict__ A, const float* __restrict__ W,
    const float* __restrict__ bias, float* __restrict__ C) {
  __shared__ float As[BK][128];
  __shared__ float Ws[BK][128];

  const int tid = threadIdx.x;
  const int tx = tid & 15;
  const int ty = tid >> 4;
  const int m0 = blockIdx.x * 128;
  const int n0 = blockIdx.y * 128;

  float acc[8][8];
#pragma unroll
  for (int i = 0; i < 8; ++i)
#pragma unroll
    for (int j = 0; j < 8; ++j) acc[i][j] = 0.f;

  for (int kt = 0; kt < 256; kt += BK) {
    // Stage A and W tiles (128 rows x BK k), transposed into LDS.
    // BK=16: 4 float4 per row, 512 float4 per matrix, 2 per thread.
#pragma unroll
    for (int it = 0; it < 2; ++it) {
      int idx = it * 256 + tid;
      int row = idx >> 2;        // 4 float4 per row
      int c4  = idx & 3;
      float4 va = *(const float4*)&A[(size_t)(m0 + row) * 256 + kt + c4 * 4];
      As[c4 * 4 + 0][row] = va.x;
      As[c4 * 4 + 1][row] = va.y;
      As[c4 * 4 + 2][row] = va.z;
      As[c4 * 4 + 3][row] = va.w;
      float4 vw = *(const float4*)&W[(size_t)(n0 + row) * 256 + kt + c4 * 4];
      Ws[c4 * 4 + 0][row] = vw.x;
      Ws[c4 * 4 + 1][row] = vw.y;
      Ws[c4 * 4 + 2][row] = vw.z;
      Ws[c4 * 4 + 3][row] = vw.w;
    }
    __syncthreads();

#pragma unroll
    for (int k = 0; k < BK; ++k) {
      float4 a0 = *(const float4*)&As[k][ty * 4];
      float4 a1 = *(const float4*)&As[k][64 + ty * 4];
      float4 b0 = *(const float4*)&Ws[k][tx * 4];
      float4 b1 = *(const float4*)&Ws[k][64 + tx * 4];
      float a[8] = {a0.x, a0.y, a0.z, a0.w, a1.x, a1.y, a1.z, a1.w};
      float b[8] = {b0.x, b0.y, b0.z, b0.w, b1.x, b1.y, b1.z, b1.w};
#pragma unroll
      for (int i = 0; i < 8; ++i)
#pragma unroll
        for (int j = 0; j < 8; ++j) acc[i][j] = fmaf(a[i], b[j], acc[i][j]);
    }
    __syncthreads();
  }

  // Epilogue: bias + store (two float4 per owned row-half).
  float bi[8];
#pragma unroll
  for (int j = 0; j < 4; ++j) {
    bi[j]     = bias[n0 + tx * 4 + j];
    bi[4 + j] = bias[n0 + 64 + tx * 4 + j];
  }
#pragma unroll
  for (int ih = 0; ih < 2; ++ih) {
#pragma unroll
    for (int i = 0; i < 4; ++i) {
      int m = m0 + ih * 64 + ty * 4 + i;
      int r = ih * 4 + i;
      float4 o0 = {acc[r][0] + bi[0], acc[r][1] + bi[1],
                   acc[r][2] + bi[2], acc[r][3] + bi[3]};
      float4 o1 = {acc[r][4] + bi[4], acc[r][5] + bi[5],
                   acc[r][6] + bi[6], acc[r][7] + bi[7]};
      size_t off = (size_t)m * 256 + n0;
      *(float4*)&C[off + tx * 4]      = o0;
      *(float4*)&C[off + 64 + tx * 4] = o1;
    }
  }
}

// ---------------------------------------------------------------------------
// Neighborhood aggregation.
// v laid out (B,H,W,C) with c = head*32 + d (matches reference reshape).
// Block = 256 threads = 4 waves; wave p handles pixel (b, h, w0+p).
// Lane owns channels c = lane*4 .. +3  (head = lane/8).
// attn tile staged in LDS (4 px x 8 heads x 49 = 6.3 KB).
// Per tap: one coalesced 1 KB v-row read per wave + 4 FMA per lane.
// sh/sw are clipped window starts (always 7 valid taps, no bounds checks).
// ---------------------------------------------------------------------------
__global__ __launch_bounds__(256) void nat_agg_f32(
    const float* __restrict__ v, const float* __restrict__ attn,
    float* __restrict__ o) {
  __shared__ float satt[4][NHEADS][KK * KK];

  const int tid  = threadIdx.x;
  const int p    = tid >> 6;       // pixel within block
  const int lane = tid & 63;
  const int head = lane >> 3;
  const int l8   = lane & 7;

  const int b  = blockIdx.z;
  const int h  = blockIdx.y;
  const int w  = blockIdx.x * 4 + p;

  // Stage this pixel's attention row (one wave stages its own pixel).
  const float* ap =
      attn + ((((size_t)b * NHEADS + head) * HH + h) * WW + w) * (KK * KK);
#pragma unroll
  for (int j = 0; j < 7; ++j) {
    int t = j * 8 + l8;
    if (t < KK * KK) satt[p][head][t] = ap[t];
  }
  __syncthreads();

  const int c  = lane * 4;
  const int sh = min(max(h - KK / 2, 0), HH - KK);
  const int sw = min(max(w - KK / 2, 0), WW - KK);

  const float* vb = v + (((size_t)b * HH + sh) * WW + sw) * CC + c;
  float4 acc = {0.f, 0.f, 0.f, 0.f};

  for (int ki = 0; ki < KK; ++ki) {
    const float* vr = vb + (size_t)ki * (WW * CC);
#pragma unroll
    for (int kj = 0; kj < KK; ++kj) {
      float wgt = satt[p][head][ki * KK + kj];
      float4 vv = *(const float4*)(vr + kj * CC);
      acc.x = fmaf(wgt, vv.x, acc.x);
      acc.y = fmaf(wgt, vv.y, acc.y);
      acc.z = fmaf(wgt, vv.z, acc.z);
      acc.w = fmaf(wgt, vv.w, acc.w);
    }
  }

  float* op = o + (((size_t)b * HH + h) * WW + w) * CC + c;
  *(float4*)op = acc;
}

// ---------------------------------------------------------------------------
// Launch: v -> d_out (scratch; fully overwritten later), o -> d_ws,
// final projection -> d_out.  Needs ws_size >= 134,217,728 bytes.
// ---------------------------------------------------------------------------
extern "C" void kernel_launch(void* const* d_in, const int* in_sizes, int n_in,
                              void* d_out, int out_size, void* d_ws,
                              size_t ws_size, hipStream_t stream) {
  const float* x    = (const float*)d_in[0];
  const float* attn = (const float*)d_in[1];
  const float* Wv   = (const float*)d_in[2];
  const float* bv   = (const float*)d_in[3];
  const float* Wp   = (const float*)d_in[4];
  const float* bp   = (const float*)d_in[5];
  float* out = (float*)d_out;

  float* v = out;             // stage 1 intermediate lives in d_out
  float* o = (float*)d_ws;    // stage 2 intermediate lives in workspace

  dim3 gemm_grid(MTOT / 128, CC / 128);

  // v = x @ Wv^T + bv
  gemm_bt_bias_f32<<<gemm_grid, 256, 0, stream>>>(x, Wv, bv, v);
  // o = NAT(attn, v)
  nat_agg_f32<<<dim3(WW / 4, HH, BATCH), 256, 0, stream>>>(v, attn, o);
  // out = o @ Wp^T + bp
  gemm_bt_bias_f32<<<gemm_grid, 256, 0, stream>>>(o, Wp, bp, out);
}

// Round 2
// 617.533 us; speedup vs baseline: 1.5722x; 1.5722x over previous
//
#include <hip/hip_runtime.h>
#include <hip/hip_bf16.h>
#include <cstdint>
#include <cstddef>

// Problem constants
#define BATCH 8
#define HH 128
#define WW 128
#define CC 256
#define NHEADS 8
#define KK 7
#define MTOT (BATCH * HH * WW)   // 131072 rows

typedef __attribute__((ext_vector_type(4))) float f32x4;
typedef __attribute__((ext_vector_type(8))) short s16x8;

// bf16 round-to-nearest-even on raw bits
__device__ __forceinline__ unsigned short f2bf_rtn(float f) {
  unsigned int u = __float_as_uint(f);
  u += 0x7FFFu + ((u >> 16) & 1u);
  return (unsigned short)(u >> 16);
}

// ---------------------------------------------------------------------------
// Split-bf16 MFMA GEMM: C[M,256] = A[M,256] @ W[256,256]^T + bias
// A = Ah + Al (bf16 hi + bf16 residual); C ~= Ah·Bh + Ah·Bl + Al·Bh.
// 128x128 tile, BK=32, 256 thr = 4 waves, wave -> 64x64 quadrant,
// mfma_f32_16x16x32_bf16, acc f32x4[4][4] per wave.
// LDS rows padded to 40 bf16 (80 B): 16B-aligned b128, 2-way banks (free).
// ---------------------------------------------------------------------------
#define BKP 40

__global__ __launch_bounds__(256) void gemm_bt_bias_split(
    const float* __restrict__ A, const float* __restrict__ Wm,
    const float* __restrict__ bias, float* __restrict__ C) {
  __shared__ unsigned short Ahs[128][BKP], Als[128][BKP],
                            Bhs[128][BKP], Bls[128][BKP];
  const int tid  = threadIdx.x;
  const int m0   = blockIdx.x * 128;
  const int n0   = blockIdx.y * 128;
  const int wave = tid >> 6;
  const int lane = tid & 63;
  const int wr   = (wave >> 1) * 64;   // wave's m offset in tile
  const int wc   = (wave & 1) * 64;    // wave's n offset in tile
  const int r16  = lane & 15;
  const int g4   = lane >> 4;

  const int srow = tid >> 1;           // staging row 0..127
  const int sk   = (tid & 1) * 16;     // staging k offset {0,16}

  f32x4 acc[4][4];
#pragma unroll
  for (int i = 0; i < 4; ++i)
#pragma unroll
    for (int j = 0; j < 4; ++j) acc[i][j] = (f32x4)0.f;

  for (int kt = 0; kt < CC; kt += 32) {
    // ---- global load (fp32) ----
    const float* ap = &A[(size_t)(m0 + srow) * CC + kt + sk];
    const float* bp = &Wm[(size_t)(n0 + srow) * CC + kt + sk];
    float av[16], bv[16];
#pragma unroll
    for (int i = 0; i < 4; ++i) {
      *(f32x4*)&av[i * 4] = *(const f32x4*)&ap[i * 4];
      *(f32x4*)&bv[i * 4] = *(const f32x4*)&bp[i * 4];
    }
    // ---- split to hi/lo bf16 ----
    s16x8 ah[2], al[2], bh[2], bl[2];
#pragma unroll
    for (int half = 0; half < 2; ++half) {
#pragma unroll
      for (int i = 0; i < 8; ++i) {
        float fa = av[half * 8 + i];
        unsigned short ha = f2bf_rtn(fa);
        float far = __uint_as_float((unsigned int)ha << 16);
        ah[half][i] = (short)ha;
        al[half][i] = (short)f2bf_rtn(fa - far);
        float fb = bv[half * 8 + i];
        unsigned short hb = f2bf_rtn(fb);
        float fbr = __uint_as_float((unsigned int)hb << 16);
        bh[half][i] = (short)hb;
        bl[half][i] = (short)f2bf_rtn(fb - fbr);
      }
    }
    __syncthreads();   // previous iteration's fragment reads are done
#pragma unroll
    for (int half = 0; half < 2; ++half) {
      *(s16x8*)&Ahs[srow][sk + half * 8] = ah[half];
      *(s16x8*)&Als[srow][sk + half * 8] = al[half];
      *(s16x8*)&Bhs[srow][sk + half * 8] = bh[half];
      *(s16x8*)&Bls[srow][sk + half * 8] = bl[half];
    }
    __syncthreads();   // tile visible

    // ---- fragments: lane holds row (r16), k = g4*8..+7 ----
    s16x8 fah[4], fal[4], fbh[4], fbl[4];
#pragma unroll
    for (int i = 0; i < 4; ++i) {
      fah[i] = *(const s16x8*)&Ahs[wr + i * 16 + r16][g4 * 8];
      fal[i] = *(const s16x8*)&Als[wr + i * 16 + r16][g4 * 8];
      fbh[i] = *(const s16x8*)&Bhs[wc + i * 16 + r16][g4 * 8];
      fbl[i] = *(const s16x8*)&Bls[wc + i * 16 + r16][g4 * 8];
    }
#pragma unroll
    for (int mi = 0; mi < 4; ++mi)
#pragma unroll
      for (int ni = 0; ni < 4; ++ni) {
        acc[mi][ni] = __builtin_amdgcn_mfma_f32_16x16x32_bf16(
            fah[mi], fbh[ni], acc[mi][ni], 0, 0, 0);
        acc[mi][ni] = __builtin_amdgcn_mfma_f32_16x16x32_bf16(
            fah[mi], fbl[ni], acc[mi][ni], 0, 0, 0);
        acc[mi][ni] = __builtin_amdgcn_mfma_f32_16x16x32_bf16(
            fal[mi], fbh[ni], acc[mi][ni], 0, 0, 0);
      }
  }

  // ---- epilogue: D[row=g4*4+i][col=r16] per fragment ----
#pragma unroll
  for (int ni = 0; ni < 4; ++ni) {
    int col = n0 + wc + ni * 16 + r16;
    float bs = bias[col];
#pragma unroll
    for (int mi = 0; mi < 4; ++mi) {
      int rowb = m0 + wr + mi * 16 + g4 * 4;
#pragma unroll
      for (int i = 0; i < 4; ++i)
        C[(size_t)(rowb + i) * CC + col] = acc[mi][ni][i] + bs;
    }
  }
}

// ---------------------------------------------------------------------------
// NAT aggregation v2: register sliding window.
// Block = 256 thr = 4 waves; block covers 32 px of one row h; wave owns a
// strip of 8 consecutive w. Lane owns 4 channels (c = lane*4, head = lane>>3).
// Per window-row ki: load the 14-column union once into registers, feed all
// 8 px x 7 taps from registers -> 4x less L2 traffic than naive.
// attn staged in LDS [8][32*49 (+4 pad)]: coalesced load, conflict-free
// broadcast reads (head stride mod 32 = 4).
// EDGE template keeps clamped register indices compile-time (no scratch).
// ---------------------------------------------------------------------------
#define ATS (32 * KK * KK + 4)   // 1572 floats per head

template <int EDGE>   // 0 interior, 1 left (w0p==0), 2 right (w0p==120)
__device__ __forceinline__ void nat_strip(const float* __restrict__ vbase,
                                          const float* __restrict__ sa,
                                          f32x4* acc) {
  for (int ki = 0; ki < KK; ++ki) {
    const float* vr = vbase + (size_t)ki * (WW * CC);
    f32x4 sreg[14];
#pragma unroll
    for (int t = 0; t < 14; ++t) sreg[t] = *(const f32x4*)(vr + t * CC);
#pragma unroll
    for (int j = 0; j < 8; ++j) {
#pragma unroll
      for (int kj = 0; kj < KK; ++kj) {
        const int idx = (EDGE == 0) ? (j + kj)
                      : (EDGE == 1) ? ((j < 3 ? 0 : j - 3) + kj)
                                    : ((j > 4 ? 7 : j + 3) + kj);
        float wg = sa[j * 49 + ki * KK + kj];
        acc[j] += wg * sreg[idx];
      }
    }
  }
}

__global__ __launch_bounds__(256) void nat_agg_v2(
    const float* __restrict__ v, const float* __restrict__ attn,
    float* __restrict__ o) {
  __shared__ float satt[NHEADS * ATS];

  const int tid = threadIdx.x;
  const int b = blockIdx.z, h = blockIdx.y;
  const int w0 = blockIdx.x * 32;

  // ---- stage attn: per head, 32 px x 49 = 1568 contiguous floats ----
  {
    const int hd = tid >> 5, l32 = tid & 31;
    const float4* src = (const float4*)
        &attn[(((((size_t)b * NHEADS + hd) * HH + h) * WW) + w0) * (KK * KK)];
    float* dst = &satt[hd * ATS];
#pragma unroll
    for (int i = 0; i < 12; ++i) {
      float4 t4 = src[i * 32 + l32];
      *(float4*)&dst[(i * 32 + l32) * 4] = t4;
    }
    if (l32 < 8) {
      float4 t4 = src[384 + l32];
      *(float4*)&dst[(384 + l32) * 4] = t4;
    }
  }
  __syncthreads();

  const int wave = tid >> 6, lane = tid & 63;
  const int w0p = w0 + wave * 8;
  const int c = lane * 4;
  const int hd = lane >> 3;
  const int sh = min(max(h - KK / 2, 0), HH - KK);

  const float* vbase = v + (size_t)(b * HH + sh) * WW * CC + c;
  const float* sa = &satt[hd * ATS + wave * 8 * (KK * KK)];

  f32x4 acc[8];
#pragma unroll
  for (int j = 0; j < 8; ++j) acc[j] = (f32x4)0.f;

  if (w0p == 0)
    nat_strip<1>(vbase, sa, acc);                       // colbase = 0
  else if (w0p == WW - 8)
    nat_strip<2>(vbase + (WW - 14) * CC, sa, acc);      // colbase = 114
  else
    nat_strip<0>(vbase + (w0p - 3) * CC, sa, acc);      // colbase = w0p-3

  float* op = o + ((size_t)(b * HH + h) * WW + w0p) * CC + c;
#pragma unroll
  for (int j = 0; j < 8; ++j) *(f32x4*)(op + j * CC) = acc[j];
}

// ---------------------------------------------------------------------------
// Launch: v -> d_out (scratch; fully overwritten later), o -> d_ws,
// final projection -> d_out.  Needs ws_size >= 134,217,728 bytes.
// ---------------------------------------------------------------------------
extern "C" void kernel_launch(void* const* d_in, const int* in_sizes, int n_in,
                              void* d_out, int out_size, void* d_ws,
                              size_t ws_size, hipStream_t stream) {
  const float* x    = (const float*)d_in[0];
  const float* attn = (const float*)d_in[1];
  const float* Wv   = (const float*)d_in[2];
  const float* bv   = (const float*)d_in[3];
  const float* Wp   = (const float*)d_in[4];
  const float* bp   = (const float*)d_in[5];
  float* out = (float*)d_out;

  float* v = out;             // stage 1 intermediate lives in d_out
  float* o = (float*)d_ws;    // stage 2 intermediate lives in workspace

  dim3 gemm_grid(MTOT / 128, CC / 128);

  // v = x @ Wv^T + bv
  gemm_bt_bias_split<<<gemm_grid, 256, 0, stream>>>(x, Wv, bv, v);
  // o = NAT(attn, v)
  nat_agg_v2<<<dim3(WW / 32, HH, BATCH), 256, 0, stream>>>(v, attn, o);
  // out = o @ Wp^T + bp
  gemm_bt_bias_split<<<gemm_grid, 256, 0, stream>>>(o, Wp, bp, out);
}